// Round 1
// 345.157 us; speedup vs baseline: 1.0199x; 1.0199x over previous
//
#include <hip/hip_runtime.h>
#include <cstdint>
#include <cstddef>

#define NUM_USERS 100000
#define NUM_ITEMS 100000
#define NUM_NODES 200000
#define NUM_EDGES 4000000
#define BATCH     4096
#define EMB       64

#define NB    782          // ceil(NUM_NODES / 256) buckets (bucket = row >> 8)
#define CAP   5632         // fixed bucket capacity: mean 5115 + 7.2 sigma
#define CHUNK 16384        // edges per block in k_part1 (245 blocks)
#define PTHREADS 1024
#define EPB   16           // CHUNK / PTHREADS
#define RPT   11           // CAP / 512: tmp records per thread in k_part2
#define NWORDS 6250        // ceil(NUM_NODES / 32) bitmap words

// ---------------- bf16 helpers (round-to-nearest-even) ----------------

__device__ __forceinline__ unsigned short f2bf(float f) {
    unsigned u = __float_as_uint(f);
    u = (u + 0x7FFFu + ((u >> 16) & 1u)) >> 16;
    return (unsigned short)u;
}
__device__ __forceinline__ float bf2f(unsigned short b) {
    return __uint_as_float(((unsigned)b) << 16);
}

// ---------------- Pass 1: cvt + batch-marking + partition (fused) ----------------
// bcur is RELATIVE (zeroed by memset); tmp position = bkt*CAP + rel.
// cvt (f32->bf16) and batch-node bitmap marking are independent side jobs
// grid-strided across this kernel's 245x1024 threads.

__global__ void k_part1(const int* __restrict__ user, const int* __restrict__ pos,
                        const int* __restrict__ neg,
                        const int* __restrict__ erow, const int* __restrict__ ecol,
                        const float* __restrict__ eval_,
                        const float* __restrict__ uemb, const float* __restrict__ iemb,
                        unsigned short* __restrict__ xb,
                        int* __restrict__ bcur,
                        unsigned* __restrict__ memb, unsigned* __restrict__ need,
                        int2* __restrict__ tmp) {
    __shared__ int hist[NB];
    __shared__ int base[NB];
    int t = threadIdx.x;
    int gid = blockIdx.x * PTHREADS + t;
    for (int i = t; i < NB; i += PTHREADS) hist[i] = 0;

    // fused cvt: f32 emb -> bf16 xb (xb consumed only by later kernels)
    const int TOT8 = (NUM_NODES * EMB) / 8;              // 1.6M chunks of 8
    const size_t UELEMS = (size_t)NUM_USERS * EMB;       // divisible by 8
    for (int i = gid; i < TOT8; i += gridDim.x * PTHREADS) {
        size_t off = (size_t)i * 8;
        const float* src = (off < UELEMS) ? (uemb + off) : (iemb + (off - UELEMS));
        float4 f0 = ((const float4*)src)[0];
        float4 f1 = ((const float4*)src)[1];
        ((ushort4*)(xb + off))[0] = make_ushort4(f2bf(f0.x), f2bf(f0.y), f2bf(f0.z), f2bf(f0.w));
        ((ushort4*)(xb + off))[1] = make_ushort4(f2bf(f1.x), f2bf(f1.y), f2bf(f1.z), f2bf(f1.w));
    }
    // fused batch-node marking: memb = rows whose edge-cols must be marked,
    // need = rows whose h1 must be computed (batch nodes themselves included)
    if (gid < 3 * BATCH) {
        int b = gid & (BATCH - 1);
        int w = gid >> 12;
        int node = (w == 0) ? user[b] : (w == 1) ? (NUM_USERS + pos[b]) : (NUM_USERS + neg[b]);
        unsigned bit = 1u << (node & 31);
        atomicOr(&memb[node >> 5], bit);
        atomicOr(&need[node >> 5], bit);
    }
    __syncthreads();

    int start = blockIdx.x * CHUNK;
    int rows[EPB], ranks[EPB];
#pragma unroll
    for (int k = 0; k < EPB; ++k) {
        int e = start + t + k * PTHREADS;
        if (e < NUM_EDGES) {
            int r = erow[e];
            rows[k]  = r;
            ranks[k] = atomicAdd(&hist[r >> 8], 1);
        } else {
            rows[k] = -1;
        }
    }
    __syncthreads();
    for (int i = t; i < NB; i += PTHREADS) {
        int c = hist[i];
        base[i] = c ? atomicAdd(&bcur[i], c) : 0;
    }
    __syncthreads();
#pragma unroll
    for (int k = 0; k < EPB; ++k) {
        int e = start + t + k * PTHREADS;
        if (rows[k] >= 0) {
            int r   = rows[k];
            int bkt = r >> 8;
            int rel = base[bkt] + ranks[k];
            if (rel < CAP)   // overflow clamp (P ~ 2e-10, deterministic input)
                tmp[bkt * CAP + rel] = make_int2(((r & 255) << 24) | ecol[e], __float_as_int(eval_[e]));
        }
    }
}

// ---------------- Pass 2: per-bucket sort -> FIXED-CAP epack + rowext ----------------
// One block per bucket, 512 threads. tmp read ONCE into registers (<=11/thread),
// reused for histogram and scatter. During scatter, records whose row is a
// batch node mark their column in `need` (those h1 rows feed k_final's gather).

__global__ void k_part2(const int* __restrict__ bcur, const int2* __restrict__ tmp,
                        const unsigned* __restrict__ memb,
                        int2* __restrict__ epack, int2* __restrict__ rowext,
                        unsigned* __restrict__ need) {
    __shared__ int cnt[256];
    __shared__ int sc[256];
    __shared__ int loc[256];
    __shared__ unsigned mw[8];
    int b = blockIdx.x, t = threadIdx.x;
    int base_row = b << 8;
    int nrows = min(256, NUM_NODES - base_row);
    int s0 = b * CAP;
    int n = min(bcur[b], CAP);
    if (t < 256) cnt[t] = 0;
    if (t < 8) {
        int wi = (base_row >> 5) + t;
        mw[t] = (wi < NWORDS) ? memb[wi] : 0u;
    }
    __syncthreads();
    int2 r[RPT];
#pragma unroll
    for (int i = 0; i < RPT; ++i) {
        int idx = t + i * 512;
        if (idx < n) {
            r[i] = tmp[s0 + idx];
            atomicAdd(&cnt[((unsigned)r[i].x) >> 24], 1);
        }
    }
    __syncthreads();
    int v = 0;
    if (t < 256) { v = cnt[t]; sc[t] = v; }
    __syncthreads();
    for (int off = 1; off < 256; off <<= 1) {
        int add = 0;
        if (t < 256 && t >= off) add = sc[t - off];
        __syncthreads();
        if (t < 256 && t >= off) sc[t] += add;
        __syncthreads();
    }
    if (t < 256) {
        int cur = s0 + sc[t] - v;   // exclusive, bucket-local
        if (t < nrows) rowext[base_row + t] = make_int2(cur, v);
        loc[t] = cur;
    }
    __syncthreads();
#pragma unroll
    for (int i = 0; i < RPT; ++i) {
        int idx = t + i * 512;
        if (idx < n) {
            int2 rec = r[i];
            unsigned rl = ((unsigned)rec.x) >> 24;
            int p = atomicAdd(&loc[rl], 1);
            int col = rec.x & 0xFFFFFF;
            epack[p] = make_int2(col, rec.y);
            if ((mw[rl >> 5] >> (rl & 31)) & 1u)
                atomicOr(&need[col >> 5], 1u << (col & 31));
        }
    }
}

// ---------------- SpMM layer 1: h1 = A * x, NEEDED ROWS ONLY ----------------
// Wave = 1 row. Rows not in `need` (h1 never read downstream) exit immediately
// (~29% of rows). Main loop is unpredicated over floor8(deg) edges; one
// predicated tail iteration handles the remainder.

__global__ void k_spmm1(const int2* __restrict__ rowext, const int2* __restrict__ epack,
                        const unsigned short* __restrict__ xb,
                        const unsigned* __restrict__ need,
                        unsigned short* __restrict__ h1) {
    int wid  = (blockIdx.x * blockDim.x + threadIdx.x) >> 6;
    int lane = threadIdx.x & 63;
    if (wid >= NUM_NODES) return;
    if (!((need[wid >> 5] >> (wid & 31)) & 1u)) return;
    int g = lane >> 4;
    int q = (lane & 15) * 4;
    int2 se = rowext[wid];
    int s = se.x, t = se.x + se.y;
    float a0 = 0.f, a1 = 0.f, a2 = 0.f, a3 = 0.f;
    int e = s;
    int tfull = s + ((t - s) & ~7);
    for (; e < tfull; e += 8) {        // unpredicated hot loop
        int2 pA = epack[e + g];
        int2 pB = epack[e + 4 + g];
        float vA = __int_as_float(pA.y);
        float vB = __int_as_float(pB.y);
        ushort4 xA = *(const ushort4*)(xb + (size_t)pA.x * EMB + q);
        ushort4 xB = *(const ushort4*)(xb + (size_t)pB.x * EMB + q);
        a0 = fmaf(vA, bf2f(xA.x), a0); a1 = fmaf(vA, bf2f(xA.y), a1);
        a2 = fmaf(vA, bf2f(xA.z), a2); a3 = fmaf(vA, bf2f(xA.w), a3);
        a0 = fmaf(vB, bf2f(xB.x), a0); a1 = fmaf(vB, bf2f(xB.y), a1);
        a2 = fmaf(vB, bf2f(xB.z), a2); a3 = fmaf(vB, bf2f(xB.w), a3);
    }
    if (e < t) {                        // predicated tail (<=1 iteration)
        int eA = e + g, eB = e + 4 + g;
        int2 pA = epack[eA < t ? eA : s];
        int2 pB = epack[eB < t ? eB : s];
        float vA = (eA < t) ? __int_as_float(pA.y) : 0.f;
        float vB = (eB < t) ? __int_as_float(pB.y) : 0.f;
        ushort4 xA = *(const ushort4*)(xb + (size_t)pA.x * EMB + q);
        ushort4 xB = *(const ushort4*)(xb + (size_t)pB.x * EMB + q);
        a0 = fmaf(vA, bf2f(xA.x), a0); a1 = fmaf(vA, bf2f(xA.y), a1);
        a2 = fmaf(vA, bf2f(xA.z), a2); a3 = fmaf(vA, bf2f(xA.w), a3);
        a0 = fmaf(vB, bf2f(xB.x), a0); a1 = fmaf(vB, bf2f(xB.y), a1);
        a2 = fmaf(vB, bf2f(xB.z), a2); a3 = fmaf(vB, bf2f(xB.w), a3);
    }
    a0 += __shfl_xor(a0, 16, 64); a1 += __shfl_xor(a1, 16, 64);
    a2 += __shfl_xor(a2, 16, 64); a3 += __shfl_xor(a3, 16, 64);
    a0 += __shfl_xor(a0, 32, 64); a1 += __shfl_xor(a1, 32, 64);
    a2 += __shfl_xor(a2, 32, 64); a3 += __shfl_xor(a3, 32, 64);
    if (lane < 16) {
        ushort4 o = make_ushort4(f2bf(a0), f2bf(a1), f2bf(a2), f2bf(a3));
        *(ushort4*)(h1 + (size_t)wid * EMB + q) = o;
    }
}

// ---------------- Fused layer 2 + scoring (same 4-edge-group gather) ----------------

__device__ __forceinline__ const float* node_ptr(int c, const float* __restrict__ uemb,
                                                 const float* __restrict__ iemb) {
    return (c < NUM_USERS) ? (uemb + (size_t)c * EMB)
                           : (iemb + (size_t)(c - NUM_USERS) * EMB);
}

__global__ void k_final(const int* __restrict__ user, const int* __restrict__ pos,
                        const int* __restrict__ neg,
                        const int2* __restrict__ rowext, const int2* __restrict__ epack,
                        const float* __restrict__ uemb, const float* __restrict__ iemb,
                        const unsigned short* __restrict__ h1, float* __restrict__ out) {
    __shared__ float lds[3 * EMB];
    int b    = blockIdx.x;
    int w    = threadIdx.x >> 6;
    int lane = threadIdx.x & 63;
    int g = lane >> 4;
    int q = (lane & 15) * 4;

    int node;
    if (w == 0)      node = user[b];
    else if (w == 1) node = NUM_USERS + pos[b];
    else             node = NUM_USERS + neg[b];

    int2 se = rowext[node];
    int s = se.x, t = se.x + se.y;
    float a0 = 0.f, a1 = 0.f, a2 = 0.f, a3 = 0.f;
    for (int e = s; e < t; e += 8) {
        int eA = e + g, eB = e + 4 + g;
        int2 pA = epack[eA < t ? eA : s];
        int2 pB = epack[eB < t ? eB : s];
        float vA = (eA < t) ? __int_as_float(pA.y) : 0.f;
        float vB = (eB < t) ? __int_as_float(pB.y) : 0.f;
        ushort4 yA = *(const ushort4*)(h1 + (size_t)pA.x * EMB + q);
        ushort4 yB = *(const ushort4*)(h1 + (size_t)pB.x * EMB + q);
        a0 = fmaf(vA, bf2f(yA.x), a0); a1 = fmaf(vA, bf2f(yA.y), a1);
        a2 = fmaf(vA, bf2f(yA.z), a2); a3 = fmaf(vA, bf2f(yA.w), a3);
        a0 = fmaf(vB, bf2f(yB.x), a0); a1 = fmaf(vB, bf2f(yB.y), a1);
        a2 = fmaf(vB, bf2f(yB.z), a2); a3 = fmaf(vB, bf2f(yB.w), a3);
    }
    a0 += __shfl_xor(a0, 16, 64); a1 += __shfl_xor(a1, 16, 64);
    a2 += __shfl_xor(a2, 16, 64); a3 += __shfl_xor(a3, 16, 64);
    a0 += __shfl_xor(a0, 32, 64); a1 += __shfl_xor(a1, 32, 64);
    a2 += __shfl_xor(a2, 32, 64); a3 += __shfl_xor(a3, 32, 64);

    if (lane < 16) {
        const float* xbp = node_ptr(node, uemb, iemb) + q;
        float4  xd = *(const float4*)xbp;
        ushort4 hn = *(const ushort4*)(h1 + (size_t)node * EMB + q);
        a0 = (a0 + xd.x + bf2f(hn.x)) / 3.0f;
        a1 = (a1 + xd.y + bf2f(hn.y)) / 3.0f;
        a2 = (a2 + xd.z + bf2f(hn.z)) / 3.0f;
        a3 = (a3 + xd.w + bf2f(hn.w)) / 3.0f;
        *(float4*)(lds + w * EMB + q) = make_float4(a0, a1, a2, a3);
    }
    __syncthreads();

    if (w < 2) {
        float prod = lds[lane] * lds[(w + 1) * EMB + lane];
        for (int off = 32; off; off >>= 1) prod += __shfl_xor(prod, off, 64);
        if (lane == 0) out[w * BATCH + b] = prod;
    }
}

// ---------------- launch ----------------

extern "C" void kernel_launch(void* const* d_in, const int* in_sizes, int n_in,
                              void* d_out, int out_size, void* d_ws, size_t ws_size,
                              hipStream_t stream) {
    const int*   user  = (const int*)d_in[0];
    const int*   pos   = (const int*)d_in[1];
    const int*   neg   = (const int*)d_in[2];
    const int*   erow  = (const int*)d_in[3];
    const int*   ecol  = (const int*)d_in[4];
    const float* eval_ = (const float*)d_in[5];
    const float* uemb  = (const float*)d_in[6];
    const float* iemb  = (const float*)d_in[7];
    float* out = (float*)d_out;

    char* ws = (char*)d_ws;
    // layout (bytes) — tmp ALIASES h1 (tmp dead before spmm1 writes h1, stream-ordered):
    //   xb      : 0          .. 25,600,000   (200000*64 bf16)
    //   h1      : 25,600,000 .. 51,200,000   (bf16)
    //   tmp     : 25,600,000 .. 60,833,792   (782*5632 int2, aliases h1)
    //   rowext  : 60,833,792 .. 62,433,792   (200000 int2)
    //   bcur    : 62,433,792 .. 62,436,920   (782 int, RELATIVE cursors)
    //   memb    : 62,436,920 .. 62,461,920   (6250 words: batch-node bitmap)
    //   need    : 62,461,920 .. 62,486,920   (6250 words: h1 rows needed)
    //   epack   : 62,486,920 .. 97,720,712   (782*5632 int2, fixed-CAP regions)
    unsigned short* xb = (unsigned short*)(ws);
    unsigned short* h1 = (unsigned short*)(ws + 25600000);
    int2* tmp      = (int2*)(ws + 25600000);
    int2* rowext   = (int2*)(ws + 60833792);
    int*  bcur     = (int*)(ws + 62433792);
    unsigned* memb = (unsigned*)(ws + 62436920);
    unsigned* need = (unsigned*)(ws + 62461920);
    int2* epack    = (int2*)(ws + 62486920);

    // zero bcur + memb + need in one contiguous memset (53,128 B)
    hipMemsetAsync(ws + 62433792, 0, 53128, stream);

    k_part1<<<(NUM_EDGES + CHUNK - 1) / CHUNK, PTHREADS, 0, stream>>>(
        user, pos, neg, erow, ecol, eval_, uemb, iemb, xb, bcur, memb, need, tmp);

    k_part2<<<NB, 512, 0, stream>>>(bcur, tmp, memb, epack, rowext, need);

    k_spmm1<<<(NUM_NODES * 64 + 255) / 256, 256, 0, stream>>>(rowext, epack, xb, need, h1);

    k_final<<<BATCH, 192, 0, stream>>>(user, pos, neg, rowext, epack,
                                       uemb, iemb, h1, out);
}

// Round 2
// 294.610 us; speedup vs baseline: 1.1949x; 1.1716x over previous
//
#include <hip/hip_runtime.h>
#include <cstdint>
#include <cstddef>

#define NUM_USERS 100000
#define NUM_ITEMS 100000
#define NUM_NODES 200000
#define NUM_EDGES 4000000
#define BATCH     4096
#define EMB       64

#define NB    391          // ceil(NUM_NODES / 512) buckets (bucket = row >> 9)
#define CAP   11264        // fixed bucket capacity: mean 10240 + 10 sigma; = 11*1024
#define CHUNK 8192         // edges per block in k_part1 (489 blocks)
#define PTHREADS 1024
#define EPB   8            // CHUNK / PTHREADS
#define RPT   11           // CAP / 1024: tmp records per thread in k_part2
#define NWORDS 6250        // ceil(NUM_NODES / 32) bitmap words

// ---------------- bf16 helpers (round-to-nearest-even) ----------------

__device__ __forceinline__ unsigned short f2bf(float f) {
    unsigned u = __float_as_uint(f);
    u = (u + 0x7FFFu + ((u >> 16) & 1u)) >> 16;
    return (unsigned short)u;
}
__device__ __forceinline__ float bf2f(unsigned short b) {
    return __uint_as_float(((unsigned)b) << 16);
}

// ---------------- Pass 1: cvt + marking + LDS-sorted partition ----------------
// Each block counting-sorts its 8192-edge chunk by 512-row bucket in LDS,
// then copies out per-bucket runs with consecutive lanes -> consecutive
// global addresses (full-line coalesced tmp writes; fixes the 2.5x write
// amplification of the old random 8-B scatter). bcur is RELATIVE (memset 0).
// Record pack: x = (row&511)<<18 | col  (9+18 bits), y = f32 val bits.

__global__ void k_part1(const int* __restrict__ user, const int* __restrict__ pos,
                        const int* __restrict__ neg,
                        const int* __restrict__ erow, const int* __restrict__ ecol,
                        const float* __restrict__ eval_,
                        const float* __restrict__ uemb, const float* __restrict__ iemb,
                        unsigned short* __restrict__ xb,
                        int* __restrict__ bcur,
                        unsigned* __restrict__ memb, unsigned* __restrict__ need,
                        int2* __restrict__ tmp) {
    __shared__ int  hist[NB];
    __shared__ int  sst[512];          // inclusive scan of hist (padded)
    __shared__ int  gb[NB];            // global base per bucket
    __shared__ int2 srec[CHUNK];       // 64 KB block-sorted records
    int t = threadIdx.x;
    int gid = blockIdx.x * PTHREADS + t;
    if (t < NB) hist[t] = 0;

    // fused cvt: f32 emb -> bf16 xb (3.2 grid-stride iters over 489x1024 threads)
    const int TOT8 = (NUM_NODES * EMB) / 8;              // 1.6M chunks of 8
    const size_t UELEMS = (size_t)NUM_USERS * EMB;       // divisible by 8
    for (int i = gid; i < TOT8; i += gridDim.x * PTHREADS) {
        size_t off = (size_t)i * 8;
        const float* src = (off < UELEMS) ? (uemb + off) : (iemb + (off - UELEMS));
        float4 f0 = ((const float4*)src)[0];
        float4 f1 = ((const float4*)src)[1];
        ((ushort4*)(xb + off))[0] = make_ushort4(f2bf(f0.x), f2bf(f0.y), f2bf(f0.z), f2bf(f0.w));
        ((ushort4*)(xb + off))[1] = make_ushort4(f2bf(f1.x), f2bf(f1.y), f2bf(f1.z), f2bf(f1.w));
    }
    // fused batch-node marking
    if (gid < 3 * BATCH) {
        int b = gid & (BATCH - 1);
        int w = gid >> 12;
        int node = (w == 0) ? user[b] : (w == 1) ? (NUM_USERS + pos[b]) : (NUM_USERS + neg[b]);
        unsigned bit = 1u << (node & 31);
        atomicOr(&memb[node >> 5], bit);
        atomicOr(&need[node >> 5], bit);
    }
    __syncthreads();

    // count phase
    int start = blockIdx.x * CHUNK;
    int rows[EPB], ranks[EPB];
#pragma unroll
    for (int k = 0; k < EPB; ++k) {
        int e = start + t + k * PTHREADS;
        if (e < NUM_EDGES) {
            int r = erow[e];
            rows[k]  = r;
            ranks[k] = atomicAdd(&hist[r >> 9], 1);
        } else {
            rows[k] = -1;
        }
    }
    __syncthreads();

    // scan hist (Hillis-Steele over 512 slots, NB=391 padded with zeros)
    if (t < 512) sst[t] = (t < NB) ? hist[t] : 0;
    __syncthreads();
    for (int off = 1; off < 512; off <<= 1) {
        int add = 0;
        if (t < 512 && t >= off) add = sst[t - off];
        __syncthreads();
        if (t < 512 && t >= off) sst[t] += add;
        __syncthreads();
    }
    // global cursor reservation (relative bcur)
    if (t < NB) gb[t] = atomicAdd(&bcur[t], hist[t]);

    // LDS scatter into block-sorted order
#pragma unroll
    for (int k = 0; k < EPB; ++k) {
        if (rows[k] >= 0) {
            int e   = start + t + k * PTHREADS;
            int r   = rows[k];
            int bkt = r >> 9;
            int lp  = sst[bkt] - hist[bkt] + ranks[k];   // excl start + rank
            srec[lp] = make_int2(((r & 511) << 18) | ecol[e], __float_as_int(eval_[e]));
        }
    }
    __syncthreads();

    // coalesced copy-out: one bucket-run per wave iteration
    int wv = t >> 6, ln = t & 63;                        // 16 waves
    for (int bkt = wv; bkt < NB; bkt += 16) {
        int c  = hist[bkt];
        int st = sst[bkt] - c;
        int g0 = gb[bkt];
        size_t base = (size_t)bkt * CAP;
        for (int j = ln; j < c; j += 64) {
            int rel = g0 + j;
            if (rel < CAP)   // overflow clamp (P ~ 1e-12, deterministic input)
                tmp[base + rel] = srec[st + j];
        }
    }
}

// ---------------- Pass 2: per-bucket sort -> FIXED-CAP epack + rowext ----------------
// One block per 512-row bucket, 1024 threads. tmp read ONCE into registers
// (RPT=11, exact CAP fit), reused for histogram and scatter. Records whose
// row is a batch node mark their column in `need`.

__global__ void k_part2(const int* __restrict__ bcur, const int2* __restrict__ tmp,
                        const unsigned* __restrict__ memb,
                        int2* __restrict__ epack, int2* __restrict__ rowext,
                        unsigned* __restrict__ need) {
    __shared__ int cnt[512];
    __shared__ int sc[512];
    __shared__ int loc[512];
    __shared__ unsigned mw[16];
    int b = blockIdx.x, t = threadIdx.x;
    int base_row = b << 9;
    int nrows = min(512, NUM_NODES - base_row);
    int s0 = b * CAP;
    int n = min(bcur[b], CAP);
    if (t < 512) cnt[t] = 0;
    if (t < 16) {
        int wi = (base_row >> 5) + t;
        mw[t] = (wi < NWORDS) ? memb[wi] : 0u;
    }
    __syncthreads();
    int2 r[RPT];
#pragma unroll
    for (int i = 0; i < RPT; ++i) {
        int idx = t + i * 1024;
        if (idx < n) {
            r[i] = tmp[s0 + idx];
            atomicAdd(&cnt[((unsigned)r[i].x) >> 18], 1);
        }
    }
    __syncthreads();
    int v = 0;
    if (t < 512) { v = cnt[t]; sc[t] = v; }
    __syncthreads();
    for (int off = 1; off < 512; off <<= 1) {
        int add = 0;
        if (t < 512 && t >= off) add = sc[t - off];
        __syncthreads();
        if (t < 512 && t >= off) sc[t] += add;
        __syncthreads();
    }
    if (t < 512) {
        int cur = s0 + sc[t] - v;   // exclusive, bucket-local
        if (t < nrows) rowext[base_row + t] = make_int2(cur, v);
        loc[t] = cur;
    }
    __syncthreads();
#pragma unroll
    for (int i = 0; i < RPT; ++i) {
        int idx = t + i * 1024;
        if (idx < n) {
            int2 rec = r[i];
            unsigned rl = ((unsigned)rec.x) >> 18;
            int p = atomicAdd(&loc[rl], 1);
            int col = rec.x & 0x3FFFF;
            epack[p] = make_int2(col, rec.y);
            if ((mw[rl >> 5] >> (rl & 31)) & 1u)
                atomicOr(&need[col >> 5], 1u << (col & 31));
        }
    }
}

// ---------------- SpMM layer 1: h1 = A * x, NEEDED ROWS ONLY ----------------

__global__ void k_spmm1(const int2* __restrict__ rowext, const int2* __restrict__ epack,
                        const unsigned short* __restrict__ xb,
                        const unsigned* __restrict__ need,
                        unsigned short* __restrict__ h1) {
    int wid  = (blockIdx.x * blockDim.x + threadIdx.x) >> 6;
    int lane = threadIdx.x & 63;
    if (wid >= NUM_NODES) return;
    if (!((need[wid >> 5] >> (wid & 31)) & 1u)) return;
    int g = lane >> 4;
    int q = (lane & 15) * 4;
    int2 se = rowext[wid];
    int s = se.x, t = se.x + se.y;
    float a0 = 0.f, a1 = 0.f, a2 = 0.f, a3 = 0.f;
    int e = s;
    int tfull = s + ((t - s) & ~7);
    for (; e < tfull; e += 8) {        // unpredicated hot loop
        int2 pA = epack[e + g];
        int2 pB = epack[e + 4 + g];
        float vA = __int_as_float(pA.y);
        float vB = __int_as_float(pB.y);
        ushort4 xA = *(const ushort4*)(xb + (size_t)pA.x * EMB + q);
        ushort4 xB = *(const ushort4*)(xb + (size_t)pB.x * EMB + q);
        a0 = fmaf(vA, bf2f(xA.x), a0); a1 = fmaf(vA, bf2f(xA.y), a1);
        a2 = fmaf(vA, bf2f(xA.z), a2); a3 = fmaf(vA, bf2f(xA.w), a3);
        a0 = fmaf(vB, bf2f(xB.x), a0); a1 = fmaf(vB, bf2f(xB.y), a1);
        a2 = fmaf(vB, bf2f(xB.z), a2); a3 = fmaf(vB, bf2f(xB.w), a3);
    }
    if (e < t) {                        // predicated tail (<=1 iteration)
        int eA = e + g, eB = e + 4 + g;
        int2 pA = epack[eA < t ? eA : s];
        int2 pB = epack[eB < t ? eB : s];
        float vA = (eA < t) ? __int_as_float(pA.y) : 0.f;
        float vB = (eB < t) ? __int_as_float(pB.y) : 0.f;
        ushort4 xA = *(const ushort4*)(xb + (size_t)pA.x * EMB + q);
        ushort4 xB = *(const ushort4*)(xb + (size_t)pB.x * EMB + q);
        a0 = fmaf(vA, bf2f(xA.x), a0); a1 = fmaf(vA, bf2f(xA.y), a1);
        a2 = fmaf(vA, bf2f(xA.z), a2); a3 = fmaf(vA, bf2f(xA.w), a3);
        a0 = fmaf(vB, bf2f(xB.x), a0); a1 = fmaf(vB, bf2f(xB.y), a1);
        a2 = fmaf(vB, bf2f(xB.z), a2); a3 = fmaf(vB, bf2f(xB.w), a3);
    }
    a0 += __shfl_xor(a0, 16, 64); a1 += __shfl_xor(a1, 16, 64);
    a2 += __shfl_xor(a2, 16, 64); a3 += __shfl_xor(a3, 16, 64);
    a0 += __shfl_xor(a0, 32, 64); a1 += __shfl_xor(a1, 32, 64);
    a2 += __shfl_xor(a2, 32, 64); a3 += __shfl_xor(a3, 32, 64);
    if (lane < 16) {
        ushort4 o = make_ushort4(f2bf(a0), f2bf(a1), f2bf(a2), f2bf(a3));
        *(ushort4*)(h1 + (size_t)wid * EMB + q) = o;
    }
}

// ---------------- Fused layer 2 + scoring (same 4-edge-group gather) ----------------

__device__ __forceinline__ const float* node_ptr(int c, const float* __restrict__ uemb,
                                                 const float* __restrict__ iemb) {
    return (c < NUM_USERS) ? (uemb + (size_t)c * EMB)
                           : (iemb + (size_t)(c - NUM_USERS) * EMB);
}

__global__ void k_final(const int* __restrict__ user, const int* __restrict__ pos,
                        const int* __restrict__ neg,
                        const int2* __restrict__ rowext, const int2* __restrict__ epack,
                        const float* __restrict__ uemb, const float* __restrict__ iemb,
                        const unsigned short* __restrict__ h1, float* __restrict__ out) {
    __shared__ float lds[3 * EMB];
    int b    = blockIdx.x;
    int w    = threadIdx.x >> 6;
    int lane = threadIdx.x & 63;
    int g = lane >> 4;
    int q = (lane & 15) * 4;

    int node;
    if (w == 0)      node = user[b];
    else if (w == 1) node = NUM_USERS + pos[b];
    else             node = NUM_USERS + neg[b];

    int2 se = rowext[node];
    int s = se.x, t = se.x + se.y;
    float a0 = 0.f, a1 = 0.f, a2 = 0.f, a3 = 0.f;
    for (int e = s; e < t; e += 8) {
        int eA = e + g, eB = e + 4 + g;
        int2 pA = epack[eA < t ? eA : s];
        int2 pB = epack[eB < t ? eB : s];
        float vA = (eA < t) ? __int_as_float(pA.y) : 0.f;
        float vB = (eB < t) ? __int_as_float(pB.y) : 0.f;
        ushort4 yA = *(const ushort4*)(h1 + (size_t)pA.x * EMB + q);
        ushort4 yB = *(const ushort4*)(h1 + (size_t)pB.x * EMB + q);
        a0 = fmaf(vA, bf2f(yA.x), a0); a1 = fmaf(vA, bf2f(yA.y), a1);
        a2 = fmaf(vA, bf2f(yA.z), a2); a3 = fmaf(vA, bf2f(yA.w), a3);
        a0 = fmaf(vB, bf2f(yB.x), a0); a1 = fmaf(vB, bf2f(yB.y), a1);
        a2 = fmaf(vB, bf2f(yB.z), a2); a3 = fmaf(vB, bf2f(yB.w), a3);
    }
    a0 += __shfl_xor(a0, 16, 64); a1 += __shfl_xor(a1, 16, 64);
    a2 += __shfl_xor(a2, 16, 64); a3 += __shfl_xor(a3, 16, 64);
    a0 += __shfl_xor(a0, 32, 64); a1 += __shfl_xor(a1, 32, 64);
    a2 += __shfl_xor(a2, 32, 64); a3 += __shfl_xor(a3, 32, 64);

    if (lane < 16) {
        const float* xbp = node_ptr(node, uemb, iemb) + q;
        float4  xd = *(const float4*)xbp;
        ushort4 hn = *(const ushort4*)(h1 + (size_t)node * EMB + q);
        a0 = (a0 + xd.x + bf2f(hn.x)) / 3.0f;
        a1 = (a1 + xd.y + bf2f(hn.y)) / 3.0f;
        a2 = (a2 + xd.z + bf2f(hn.z)) / 3.0f;
        a3 = (a3 + xd.w + bf2f(hn.w)) / 3.0f;
        *(float4*)(lds + w * EMB + q) = make_float4(a0, a1, a2, a3);
    }
    __syncthreads();

    if (w < 2) {
        float prod = lds[lane] * lds[(w + 1) * EMB + lane];
        for (int off = 32; off; off >>= 1) prod += __shfl_xor(prod, off, 64);
        if (lane == 0) out[w * BATCH + b] = prod;
    }
}

// ---------------- launch ----------------

extern "C" void kernel_launch(void* const* d_in, const int* in_sizes, int n_in,
                              void* d_out, int out_size, void* d_ws, size_t ws_size,
                              hipStream_t stream) {
    const int*   user  = (const int*)d_in[0];
    const int*   pos   = (const int*)d_in[1];
    const int*   neg   = (const int*)d_in[2];
    const int*   erow  = (const int*)d_in[3];
    const int*   ecol  = (const int*)d_in[4];
    const float* eval_ = (const float*)d_in[5];
    const float* uemb  = (const float*)d_in[6];
    const float* iemb  = (const float*)d_in[7];
    float* out = (float*)d_out;

    char* ws = (char*)d_ws;
    // layout (bytes) — tmp ALIASES h1 (tmp dead before spmm1 writes h1, stream-ordered):
    //   xb      : 0          .. 25,600,000   (200000*64 bf16)
    //   h1      : 25,600,000 .. 51,200,000   (bf16)
    //   tmp     : 25,600,000 .. 60,833,792   (391*11264 int2, aliases h1)
    //   rowext  : 60,833,792 .. 62,433,792   (200000 int2)
    //   bcur    : 62,433,792 .. 62,435,360   (392 int slots, RELATIVE cursors)
    //   memb    : 62,435,360 .. 62,460,360   (6250 words: batch-node bitmap)
    //   need    : 62,460,360 .. 62,485,360   (6250 words: h1 rows needed)
    //   epack   : 62,485,360 .. 97,719,152   (391*11264 int2, fixed-CAP regions)
    unsigned short* xb = (unsigned short*)(ws);
    unsigned short* h1 = (unsigned short*)(ws + 25600000);
    int2* tmp      = (int2*)(ws + 25600000);
    int2* rowext   = (int2*)(ws + 60833792);
    int*  bcur     = (int*)(ws + 62433792);
    unsigned* memb = (unsigned*)(ws + 62435360);
    unsigned* need = (unsigned*)(ws + 62460360);
    int2* epack    = (int2*)(ws + 62485360);

    // zero bcur + memb + need in one contiguous memset (51,568 B)
    hipMemsetAsync(ws + 62433792, 0, 51568, stream);

    k_part1<<<(NUM_EDGES + CHUNK - 1) / CHUNK, PTHREADS, 0, stream>>>(
        user, pos, neg, erow, ecol, eval_, uemb, iemb, xb, bcur, memb, need, tmp);

    k_part2<<<NB, 1024, 0, stream>>>(bcur, tmp, memb, epack, rowext, need);

    k_spmm1<<<(NUM_NODES * 64 + 255) / 256, 256, 0, stream>>>(rowext, epack, xb, need, h1);

    k_final<<<BATCH, 192, 0, stream>>>(user, pos, neg, rowext, epack,
                                       uemb, iemb, h1, out);
}